// Round 5
// baseline (43.166 us; speedup 1.0000x reference)
//
#include <hip/hip_runtime.h>

// PatchStd: out = sqrt( boxconv7(x^2) - boxconv7(x)^2 ), uniform 7x7 weight w.
// x: [16, 1, 1024, 1024] fp32, zero padding 3 on each side.
//
// Uniform weight => conv = w * windowed sum. Thread owns 4 adjacent output
// cols and an 8-row strip (TPB=256, 2048 blocks — the round-2 sweet spot).
// Vertical window kept as RUNNING sums: vh += h(new) - h(old). The row
// leaving the window is RE-LOADED from cache (same thread touched it 7 rows
// earlier; ~32KB/block working set -> L1/L2 hit) instead of keeping a 7-deep
// hsum ring — round 4 showed ring+prefetch state (VGPR 88) kills occupancy,
// and occupancy is worth more than VALU here. New-row loads double-buffered
// (1 ahead). Target VGPR <= ~72 for 7 waves/SIMD.

#define IMG_W 1024
#define IMG_H 1024
#define SH    8             // output rows per block strip
#define TPB   256           // threads/block; 4 cols/thread -> 1024 cols

__global__ __launch_bounds__(TPB) void patchstd_kernel(
    const float* __restrict__ img, const float* __restrict__ wptr,
    float* __restrict__ out)
{
    const int tx = threadIdx.x;
    const int c0 = tx << 2;                       // first of 4 output cols
    const int y0 = blockIdx.y * SH;               // first output row of strip
    const float* base  = img + (size_t)blockIdx.z * (IMG_W * IMG_H);
    float*       obase = out + (size_t)blockIdx.z * (IMG_W * IMG_H);
    const float w = wptr[0];

    const bool interior = (tx > 0) && (tx < 255); // all 12 cols in-range

    float vh[4] = {0.f, 0.f, 0.f, 0.f};           // running vertical sums of h
    float vq[4] = {0.f, 0.f, 0.f, 0.f};           // running vertical sums of q
    float b[2][12];                               // rotating new-row buffers

    // Load 12 raw pixels (cols c0-4 .. c0+7) of input row `row`; zeros outside.
    auto load_raw = [&](int row, float* v) {
        if (row >= 0 && row < IMG_H) {
            const float* rp = base + row * IMG_W;
            if (interior) {
                float4 a  = *reinterpret_cast<const float4*>(rp + c0 - 4);
                float4 bb = *reinterpret_cast<const float4*>(rp + c0);
                float4 c  = *reinterpret_cast<const float4*>(rp + c0 + 4);
                v[0]=a.x;  v[1]=a.y;  v[2]=a.z;   v[3]=a.w;
                v[4]=bb.x; v[5]=bb.y; v[6]=bb.z;  v[7]=bb.w;
                v[8]=c.x;  v[9]=c.y;  v[10]=c.z;  v[11]=c.w;
            } else {
                #pragma unroll
                for (int i = 0; i < 12; ++i) {
                    int col = c0 - 4 + i;
                    v[i] = (col >= 0 && col < IMG_W) ? rp[col] : 0.f;
                }
            }
        } else {
            #pragma unroll
            for (int i = 0; i < 12; ++i) v[i] = 0.f;
        }
    };

    // Horizontal 7-sums for the 4 output cols from 12 raw values.
    // window for output col (c0+k) = v[k+1 .. k+7]
    auto hsum = [&](const float* v, float* h, float* q) {
        float s = v[1]+v[2]+v[3]+v[4]+v[5]+v[6]+v[7];
        h[0] = s;
        s = s - v[1] + v[8];  h[1] = s;
        s = s - v[2] + v[9];  h[2] = s;
        h[3] = s - v[3] + v[10];
        float sq[11];
        #pragma unroll
        for (int i = 1; i <= 10; ++i) sq[i] = v[i] * v[i];
        float t = sq[1]+sq[2]+sq[3]+sq[4]+sq[5]+sq[6]+sq[7];
        q[0] = t;
        t = t - sq[1] + sq[8];  q[1] = t;
        t = t - sq[2] + sq[9];  q[2] = t;
        q[3] = t - sq[3] + sq[10];
    };

    // Prologue: rows y0-3 .. y0+2 accumulated into vh/vq, double-buffered.
    // Exits with b0 = row y0+3, b1 = row y0+4 (main loop's first new rows).
    load_raw(y0 - 3, b[0]);
    load_raw(y0 - 2, b[1]);
    #pragma unroll
    for (int j = 0; j < 6; ++j) {
        float h[4], q[4];
        hsum(b[j & 1], h, q);
        load_raw(y0 - 1 + j, b[j & 1]);           // j=0 -> y0-1 ... j=5 -> y0+4
        #pragma unroll
        for (int k = 0; k < 4; ++k) { vh[k] += h[k]; vq[k] += q[k]; }
    }

    // Main loop (full unroll: buffer index + guards static). Iteration rr:
    //   add new row y0+rr+3 (from b[rr&1]), subtract old row y0+rr-4
    //   (re-loaded from cache; rr=0 needs no subtraction), emit row y0+rr.
    #pragma unroll
    for (int rr = 0; rr < SH; ++rr) {
        float od[12];
        if (rr >= 1) load_raw(y0 + rr - 4, od);   // cache-resident old row

        float hn[4], qn[4];
        hsum(b[rr & 1], hn, qn);
        if (rr <= 5) load_raw(y0 + rr + 5, b[rr & 1]);  // refill, 1 ahead

        float o[4];
        if (rr >= 1) {
            float ho[4], qo[4];
            hsum(od, ho, qo);
            #pragma unroll
            for (int k = 0; k < 4; ++k) {
                vh[k] += hn[k] - ho[k];
                vq[k] += qn[k] - qo[k];
            }
        } else {
            #pragma unroll
            for (int k = 0; k < 4; ++k) { vh[k] += hn[k]; vq[k] += qn[k]; }
        }
        #pragma unroll
        for (int k = 0; k < 4; ++k) {
            float mean = w * vh[k];
            float var  = fmaf(w, vq[k], -(mean * mean));
            o[k] = sqrtf(fmaxf(var, 0.f));
        }
        *reinterpret_cast<float4*>(obase + (size_t)(y0 + rr) * IMG_W + c0) =
            make_float4(o[0], o[1], o[2], o[3]);
    }
}

extern "C" void kernel_launch(void* const* d_in, const int* in_sizes, int n_in,
                              void* d_out, int out_size, void* d_ws, size_t ws_size,
                              hipStream_t stream) {
    const float* img = (const float*)d_in[0];
    const float* wt  = (const float*)d_in[1];
    float* out = (float*)d_out;
    const int batch = in_sizes[0] / (IMG_W * IMG_H);   // 16
    dim3 grid(1, IMG_H / SH, batch);                   // 2048 blocks
    patchstd_kernel<<<grid, dim3(TPB, 1, 1), 0, stream>>>(img, wt, out);
}